// Round 2
// baseline (43750.635 us; speedup 1.0000x reference)
//
#include <hip/hip_runtime.h>

// PredCells: L=6, H=1024, C=56, T=256.
// Persistent cooperative kernel: 256 WGs x 512 thr, custom grid barrier.
// Weights converted to bf16 into d_ws each call (graph-safe, same work every call).
//
// Per step t (p = t&1, q = p^1), 8 grid barriers:
//   A1: TD0=|x_t-recon1| (per-WG LDS), BU0=W0@TD0 (per-WG LDS, redundant),
//       z1=WihL0@BU0+WihR0@TD[q][0]+Whh0@h[q][0]+b -> gates -> h[p][0],c[0],
//       TD[p][0]=|h-reconR[0]|                                   BARRIER
//   B1: BU=Wmid0@TD[p][0]+b ; reconR[3]=Vmid3@h[q][4]+b (top recon from prev
//       step's h_top); recon1=V1@h[p][0]+b                       BARRIER
//   A2/B2, A3/B3, A4/B4 analogous (B_l: BU=Wmid[l-1]@TD[p][l-1],
//       reconR[l-2]=Vmid[l-2]@h[p][l-1])                         BARRIER each
//   A5: z=WihT@BU+WhhT@h[q][4]+b -> h[p][4],c[4]   (no barrier; A5 touches only
//       layer-4 state + BU, next step's A1 touches layer-0 state — disjoint)
// Loss: thread-local accumulation, block reduce + atomicAdd at the end.

#define NWG 256
#define NTHR 512

struct PCParams {
  const unsigned short *WihL, *WihR, *WhhM, *WihT, *WhhT, *Wmid, *Vmid, *V1, *W0;
  const float *b_mid, *b_top, *Wmid_b, *Vmid_b, *V1_b, *W0_b, *x;
  float *h, *c, *TD, *recon1, *reconR, *BU;
  unsigned *cnt;
  float *out;
};

__device__ __forceinline__ float bf2f(unsigned v16) {
  union { unsigned u; float f; } x; x.u = v16 << 16; return x.f;
}
__device__ __forceinline__ unsigned short f2bf(float f) {
  union { float f; unsigned u; } x; x.f = f;
  unsigned u = x.u;
  return (unsigned short)((u + 0x7fffu + ((u >> 16) & 1u)) >> 16);  // RNE
}

// ---------------- conversion kernels (run every call) ----------------
__global__ void cvt_mat(const float* __restrict__ src, unsigned short* __restrict__ dst,
                        long nchunks, int cpr, long src_ld, long src_off) {
  long i0 = (long)blockIdx.x * blockDim.x + threadIdx.x;
  long stride = (long)gridDim.x * blockDim.x;
  for (long i = i0; i < nchunks; i += stride) {
    long r = i / cpr;
    long cc = (i - r * cpr) * 8;
    const float* s = src + r * src_ld + src_off + cc;
    float4 a = *(const float4*)s;
    float4 b = *(const float4*)(s + 4);
    union { unsigned short us[8]; uint4 v; } o;
    o.us[0] = f2bf(a.x); o.us[1] = f2bf(a.y); o.us[2] = f2bf(a.z); o.us[3] = f2bf(a.w);
    o.us[4] = f2bf(b.x); o.us[5] = f2bf(b.y); o.us[6] = f2bf(b.z); o.us[7] = f2bf(b.w);
    *(uint4*)(dst + i * 8) = o.v;
  }
}

__global__ void cvt_w0(const float* __restrict__ src, unsigned short* __restrict__ dst) {
  int i = blockIdx.x * blockDim.x + threadIdx.x;   // 1024 x 64 (56 cols + zero pad)
  if (i < 1024 * 64) {
    int r = i >> 6, cc = i & 63;
    float v = (cc < 56) ? src[r * 56 + cc] : 0.f;
    dst[i] = f2bf(v);
  }
}

// ---------------- persistent kernel helpers ----------------
__device__ __forceinline__ void gbar(unsigned* cnt, unsigned target) {
  __syncthreads();
  if (threadIdx.x == 0) {
    __threadfence();  // release prior stores agent-wide
    __hip_atomic_fetch_add(cnt, 1u, __ATOMIC_RELAXED, __HIP_MEMORY_SCOPE_AGENT);
    while (__hip_atomic_load(cnt, __ATOMIC_RELAXED, __HIP_MEMORY_SCOPE_AGENT) < target)
      __builtin_amdgcn_s_sleep(2);
    __threadfence();  // acquire before consuming remote data
  }
  __syncthreads();
}

// 1024-dot, 32-way sliced (s = 0..31), 4 chunks of 8 bf16 weights each.
__device__ __forceinline__ float dot1024(const unsigned short* __restrict__ wrow,
                                         const float* xv, int s) {
  float acc = 0.f;
#pragma unroll
  for (int j = 0; j < 4; ++j) {
    int e = j * 256 + s * 8;
    uint4 wv = *(const uint4*)(wrow + e);
    float4 x0 = *(const float4*)(xv + e);
    float4 x1 = *(const float4*)(xv + e + 4);
    acc += bf2f(wv.x & 0xffffu) * x0.x;
    acc += bf2f(wv.x >> 16)     * x0.y;
    acc += bf2f(wv.y & 0xffffu) * x0.z;
    acc += bf2f(wv.y >> 16)     * x0.w;
    acc += bf2f(wv.z & 0xffffu) * x1.x;
    acc += bf2f(wv.z >> 16)     * x1.y;
    acc += bf2f(wv.w & 0xffffu) * x1.z;
    acc += bf2f(wv.w >> 16)     * x1.w;
  }
  return acc;
}

// 1024-dot, 64-way sliced (s = 0..63), 2 chunks of 8.
__device__ __forceinline__ float dotB(const unsigned short* __restrict__ wrow,
                                      const float* __restrict__ xv, int s) {
  float acc = 0.f;
#pragma unroll
  for (int j = 0; j < 2; ++j) {
    int e = j * 512 + s * 8;
    uint4 wv = *(const uint4*)(wrow + e);
    float4 x0 = *(const float4*)(xv + e);
    float4 x1 = *(const float4*)(xv + e + 4);
    acc += bf2f(wv.x & 0xffffu) * x0.x;
    acc += bf2f(wv.x >> 16)     * x0.y;
    acc += bf2f(wv.y & 0xffffu) * x0.z;
    acc += bf2f(wv.y >> 16)     * x0.w;
    acc += bf2f(wv.z & 0xffffu) * x1.x;
    acc += bf2f(wv.z >> 16)     * x1.y;
    acc += bf2f(wv.w & 0xffffu) * x1.z;
    acc += bf2f(wv.w >> 16)     * x1.w;
  }
  return acc;
}

__device__ __forceinline__ void doBrow(const unsigned short* mat, const float* xv,
                                       const float* bias, float* dst, int rr, int s) {
  float acc = dotB(mat + (size_t)rr * 1024, xv, s);
#pragma unroll
  for (int m = 32; m >= 1; m >>= 1) acc += __shfl_xor(acc, m);
  if (s == 0) dst[rr] = acc + bias[rr];
}

// One LSTM z-stage: 16 z-rows/WG (4 units x 4 gates), 32 threads per row.
__device__ void stageA(const unsigned short* mL, const unsigned short* mR,
                       const unsigned short* mH, const float* xBU, const float* xTD,
                       const float* xH, const float* bias, float* h_out, float* c_st,
                       float* td_out, const float* rec_in, float& loss, float* lds_z) {
  const int tid = threadIdx.x;
  const int rl = tid >> 5, s = tid & 31;   // row_local 0..15, slice 0..31
  const int ul = rl & 3, g = rl >> 2;      // unit-in-quad, gate
  const int U = blockIdx.x << 2;           // unit base for this WG
  const size_t zrow = (size_t)((g << 10) + U + ul);
  float acc = dot1024(mL + zrow * 1024, xBU, s);
  if (mR) acc += dot1024(mR + zrow * 1024, xTD, s);
  acc += dot1024(mH + zrow * 1024, xH, s);
#pragma unroll
  for (int m = 16; m >= 1; m >>= 1) acc += __shfl_xor(acc, m);
  if (s == 0) lds_z[rl] = acc;
  __syncthreads();
  if (tid < 4) {
    const int u = U + tid;
    float zi = lds_z[tid]      + bias[u];
    float zf = lds_z[4 + tid]  + bias[1024 + u];
    float zg = lds_z[8 + tid]  + bias[2048 + u];
    float zo = lds_z[12 + tid] + bias[3072 + u];
    float co = c_st[u];
    float ig = 1.f / (1.f + expf(-zi));
    float fg = 1.f / (1.f + expf(-zf));
    float gt = tanhf(zg);
    float og = 1.f / (1.f + expf(-zo));
    float cn = fg * co + ig * gt;
    float hn = og * tanhf(cn);
    c_st[u] = cn;
    h_out[u] = hn;
    if (td_out) {
      float td = fabsf(hn - rec_in[u]);
      td_out[u] = td;
      loss += td;
    }
  }
  __syncthreads();
}

__global__ __launch_bounds__(NTHR) void predcells_main(PCParams P) {
  __shared__ __align__(16) float lds_bu0[1024];
  __shared__ __align__(16) float lds_td0[64];
  __shared__ float lds_z[16];
  __shared__ float lds_red[8];
  const int tid = threadIdx.x;
  const int wg = blockIdx.x;
  float loss = 0.f;
  unsigned bar = 0;

  for (int t = 0; t < 256; ++t) {
    const int p = t & 1, q = p ^ 1;
    float* h_p  = P.h + p * 5120;
    float* h_q  = P.h + q * 5120;
    float* TD_p = P.TD + p * 4096;
    float* TD_q = P.TD + q * 4096;

    // ---------------- A1 ----------------
    if (tid < 64)
      lds_td0[tid] = (tid < 56) ? fabsf(P.x[t * 56 + tid] - P.recon1[tid]) : 0.f;
    __syncthreads();
    if (wg == 0 && tid < 56) loss += lds_td0[tid];
    {
#pragma unroll
      for (int rr = 0; rr < 2; ++rr) {
        int r = tid * 2 + rr;
        float acc = P.W0_b[r];
#pragma unroll
        for (int k = 0; k < 8; ++k) {
          uint4 wv = *(const uint4*)(P.W0 + r * 64 + k * 8);
          acc += bf2f(wv.x & 0xffffu) * lds_td0[k * 8 + 0];
          acc += bf2f(wv.x >> 16)     * lds_td0[k * 8 + 1];
          acc += bf2f(wv.y & 0xffffu) * lds_td0[k * 8 + 2];
          acc += bf2f(wv.y >> 16)     * lds_td0[k * 8 + 3];
          acc += bf2f(wv.z & 0xffffu) * lds_td0[k * 8 + 4];
          acc += bf2f(wv.z >> 16)     * lds_td0[k * 8 + 5];
          acc += bf2f(wv.w & 0xffffu) * lds_td0[k * 8 + 6];
          acc += bf2f(wv.w >> 16)     * lds_td0[k * 8 + 7];
        }
        lds_bu0[r] = acc;
      }
    }
    __syncthreads();
    stageA(P.WihL, P.WihR, P.WhhM, lds_bu0, TD_q, h_q, P.b_mid,
           h_p, P.c, TD_p, P.reconR, loss, lds_z);
    ++bar; gbar(P.cnt, bar * NWG);

    // ---------------- B1 ----------------
    {
      const int s = tid & 63, rl = tid >> 6;
      const int r = (wg << 3) + rl;
      if (r < 1024)
        doBrow(P.Wmid, TD_p, P.Wmid_b, P.BU, r, s);
      else
        doBrow(P.Vmid + 3u * 1048576u, h_q + 4096, P.Vmid_b + 3072, P.reconR + 3072, r - 1024, s);
      if (wg < 56 && rl == 0)
        doBrow(P.V1, h_p, P.V1_b, P.recon1, wg, s);
    }
    ++bar; gbar(P.cnt, bar * NWG);

    // ---------------- A2 ----------------
    stageA(P.WihL + 4194304, P.WihR + 4194304, P.WhhM + 4194304, P.BU,
           TD_q + 1024, h_q + 1024, P.b_mid + 4096, h_p + 1024, P.c + 1024,
           TD_p + 1024, P.reconR + 1024, loss, lds_z);
    ++bar; gbar(P.cnt, bar * NWG);

    // ---------------- B2 ----------------
    {
      const int s = tid & 63, rl = tid >> 6;
      const int r = (wg << 3) + rl;
      if (r < 1024)
        doBrow(P.Wmid + 1048576, TD_p + 1024, P.Wmid_b + 1024, P.BU, r, s);
      else
        doBrow(P.Vmid, h_p + 1024, P.Vmid_b, P.reconR, r - 1024, s);
    }
    ++bar; gbar(P.cnt, bar * NWG);

    // ---------------- A3 ----------------
    stageA(P.WihL + 2 * 4194304, P.WihR + 2 * 4194304, P.WhhM + 2 * 4194304, P.BU,
           TD_q + 2048, h_q + 2048, P.b_mid + 8192, h_p + 2048, P.c + 2048,
           TD_p + 2048, P.reconR + 2048, loss, lds_z);
    ++bar; gbar(P.cnt, bar * NWG);

    // ---------------- B3 ----------------
    {
      const int s = tid & 63, rl = tid >> 6;
      const int r = (wg << 3) + rl;
      if (r < 1024)
        doBrow(P.Wmid + 2 * 1048576, TD_p + 2048, P.Wmid_b + 2048, P.BU, r, s);
      else
        doBrow(P.Vmid + 1048576, h_p + 2048, P.Vmid_b + 1024, P.reconR + 1024, r - 1024, s);
    }
    ++bar; gbar(P.cnt, bar * NWG);

    // ---------------- A4 ----------------
    stageA(P.WihL + 3 * 4194304, P.WihR + 3 * 4194304, P.WhhM + 3 * 4194304, P.BU,
           TD_q + 3072, h_q + 3072, P.b_mid + 12288, h_p + 3072, P.c + 3072,
           TD_p + 3072, P.reconR + 3072, loss, lds_z);
    ++bar; gbar(P.cnt, bar * NWG);

    // ---------------- B4 ----------------
    {
      const int s = tid & 63, rl = tid >> 6;
      const int r = (wg << 3) + rl;
      if (r < 1024)
        doBrow(P.Wmid + 3 * 1048576, TD_p + 3072, P.Wmid_b + 3072, P.BU, r, s);
      else
        doBrow(P.Vmid + 2 * 1048576, h_p + 3072, P.Vmid_b + 2048, P.reconR + 2048, r - 1024, s);
    }
    ++bar; gbar(P.cnt, bar * NWG);

    // ---------------- A5 (top; no barrier — disjoint from next A1) ----------------
    stageA(P.WihT, nullptr, P.WhhT, P.BU, nullptr, h_q + 4096, P.b_top,
           h_p + 4096, P.c + 4096, nullptr, nullptr, loss, lds_z);
  }

  // final loss reduction
#pragma unroll
  for (int m = 1; m < 64; m <<= 1) loss += __shfl_xor(loss, m);
  if ((tid & 63) == 0) lds_red[tid >> 6] = loss;
  __syncthreads();
  if (tid == 0) {
    float s = 0.f;
#pragma unroll
    for (int i = 0; i < 8; ++i) s += lds_red[i];
    atomicAdd(P.out, s);
  }
}

// ---------------- host ----------------
extern "C" void kernel_launch(void* const* d_in, const int* in_sizes, int n_in,
                              void* d_out, int out_size, void* d_ws, size_t ws_size,
                              hipStream_t stream) {
  const float* x       = (const float*)d_in[0];
  const float* W0_w    = (const float*)d_in[1];
  const float* W0_b    = (const float*)d_in[2];
  const float* Wmid_w  = (const float*)d_in[3];
  const float* Wmid_b  = (const float*)d_in[4];
  const float* V1_w    = (const float*)d_in[5];
  const float* V1_b    = (const float*)d_in[6];
  const float* Vmid_w  = (const float*)d_in[7];
  const float* Vmid_b  = (const float*)d_in[8];
  const float* Wih_mid = (const float*)d_in[9];
  const float* Whh_mid = (const float*)d_in[10];
  const float* b_mid   = (const float*)d_in[11];
  const float* Wih_top = (const float*)d_in[12];
  const float* Whh_top = (const float*)d_in[13];
  const float* b_top   = (const float*)d_in[14];

  char* base = (char*)d_ws;
  size_t off = 0;
  auto carve = [&](size_t bytes) -> char* {
    char* ptr = base + off;
    off = (off + bytes + 255) & ~(size_t)255;
    return ptr;
  };
  unsigned* cnt = (unsigned*)carve(4);
  float* h      = (float*)carve((size_t)2 * 5 * 1024 * 4);
  float* c      = (float*)carve((size_t)5 * 1024 * 4);
  float* TD     = (float*)carve((size_t)2 * 4 * 1024 * 4);
  float* recon1 = (float*)carve((size_t)56 * 4);
  float* reconR = (float*)carve((size_t)4 * 1024 * 4);
  float* BU     = (float*)carve((size_t)1024 * 4);
  size_t state_bytes = off;
  unsigned short* WihL = (unsigned short*)carve((size_t)4 * 4096 * 1024 * 2);
  unsigned short* WihR = (unsigned short*)carve((size_t)4 * 4096 * 1024 * 2);
  unsigned short* WhhM = (unsigned short*)carve((size_t)4 * 4096 * 1024 * 2);
  unsigned short* WihT = (unsigned short*)carve((size_t)4096 * 1024 * 2);
  unsigned short* WhhT = (unsigned short*)carve((size_t)4096 * 1024 * 2);
  unsigned short* Wmid = (unsigned short*)carve((size_t)4 * 1024 * 1024 * 2);
  unsigned short* Vmid = (unsigned short*)carve((size_t)4 * 1024 * 1024 * 2);
  unsigned short* V1   = (unsigned short*)carve((size_t)56 * 1024 * 2);
  unsigned short* W0   = (unsigned short*)carve((size_t)1024 * 64 * 2);

  if (off > ws_size) {           // clean-fail signal: output stays 0
    hipMemsetAsync(d_out, 0, 4, stream);
    return;
  }

  hipMemsetAsync(d_ws, 0, state_bytes, stream);   // zero state + barrier counter
  hipMemsetAsync(d_out, 0, 4, stream);

  const int CB = 256, CG = 2048;
  hipLaunchKernelGGL(cvt_mat, dim3(CG), dim3(CB), 0, stream, Wih_mid, WihL, (long)16384 * 128, 128, (long)2048, (long)0);
  hipLaunchKernelGGL(cvt_mat, dim3(CG), dim3(CB), 0, stream, Wih_mid, WihR, (long)16384 * 128, 128, (long)2048, (long)1024);
  hipLaunchKernelGGL(cvt_mat, dim3(CG), dim3(CB), 0, stream, Whh_mid, WhhM, (long)16384 * 128, 128, (long)1024, (long)0);
  hipLaunchKernelGGL(cvt_mat, dim3(CG), dim3(CB), 0, stream, Wih_top, WihT, (long)4096 * 128, 128, (long)1024, (long)0);
  hipLaunchKernelGGL(cvt_mat, dim3(CG), dim3(CB), 0, stream, Whh_top, WhhT, (long)4096 * 128, 128, (long)1024, (long)0);
  hipLaunchKernelGGL(cvt_mat, dim3(CG), dim3(CB), 0, stream, Wmid_w, Wmid, (long)4096 * 128, 128, (long)1024, (long)0);
  hipLaunchKernelGGL(cvt_mat, dim3(CG), dim3(CB), 0, stream, Vmid_w, Vmid, (long)4096 * 128, 128, (long)1024, (long)0);
  hipLaunchKernelGGL(cvt_mat, dim3(CG), dim3(CB), 0, stream, V1_w, V1, (long)56 * 128, 128, (long)1024, (long)0);
  hipLaunchKernelGGL(cvt_w0, dim3(256), dim3(256), 0, stream, W0_w, W0);

  PCParams P{WihL, WihR, WhhM, WihT, WhhT, Wmid, Vmid, V1, W0,
             b_mid, b_top, Wmid_b, Vmid_b, V1_b, W0_b, x,
             h, c, TD, recon1, reconR, BU, cnt, (float*)d_out};

  // Cooperative launch guarantees all 256 WGs are co-resident (required by the
  // spin barrier). Fall back to a plain launch if coop launch is rejected
  // (e.g. inside graph capture on some ROCm versions); with 256 WGs x 8 waves
  // on 256 CUs a plain launch is co-resident in practice.
  void* args[] = { (void*)&P };
  hipError_t e = hipLaunchCooperativeKernel((const void*)predcells_main,
                                            dim3(NWG), dim3(NTHR), args, 0, stream);
  if (e != hipSuccess) {
    hipLaunchKernelGGL(predcells_main, dim3(NWG), dim3(NTHR), 0, stream, P);
  }
}